// Round 6
// baseline (428.938 us; speedup 1.0000x reference)
//
#include <hip/hip_runtime.h>
#include <hip/hip_bf16.h>
#include <stdint.h>

#define NTOK 49
#define DIMC 128
#define NHEAD 4
#define SCALE 0.17677669529663687f

typedef __bf16 bf16;
typedef __bf16 bf16x8 __attribute__((ext_vector_type(8)));
typedef __bf16 bf16x4 __attribute__((ext_vector_type(4)));
typedef float  f32x4  __attribute__((ext_vector_type(4)));
typedef short  s16x4  __attribute__((ext_vector_type(4)));

// ---- LDS (bf16 elems), total 32768 elems = 65536 B -> 2 blocks/CU ----
// K  [256][32] @0      rows h*64+tok, col d-within-head (plain)
// QO [256][32] @8192   Q (phase A->B, plain cols) then O (phase B->C, permuted cols)
// VT [128][64] @16384  rows h*32+d, col m (plain)
// X  [64][128] @24576  x rows tok (restaged each window in phase B)
// All regions XOR-swizzled (granule-preserving), patterns verified <=2-way.
#define K_OFF  0
#define QO_OFF 8192
#define VT_OFF 16384
#define X_OFF  24576
#define SM_BYTES (32768 * 2)

// d_ws layout (bytes): mask_b bf16 [64][64][64] @0 (524288);
// bias_b bf16 [64][4][64] @524288 (32768); qkvw_b @557056 (98304);
// pw_b (A-frag permuted) @655360 (32768)
#define WS_BIAS_OFF  524288
#define WS_QKVW_OFF  557056
#define WS_PW_OFF    655360

__device__ __forceinline__ f32x4 mfmaK32(bf16x8 a, bf16x8 b, f32x4 c) {
  return __builtin_amdgcn_mfma_f32_16x16x32_bf16(a, b, c, 0, 0, 0);
}
__device__ __forceinline__ f32x4 mfmaK16(bf16x4 a, bf16x4 b, f32x4 c) {
#if __has_builtin(__builtin_amdgcn_mfma_f32_16x16x16bf16_1k)
  return __builtin_amdgcn_mfma_f32_16x16x16bf16_1k(*(s16x4*)&a, *(s16x4*)&b, c,
                                                   0, 0, 0);
#else
  f32x4 d;
  asm("v_mfma_f32_16x16x16_bf16 %0, %1, %2, %3"
      : "=v"(d) : "v"(a), "v"(b), "v"(c));
  return d;
#endif
}
// XOR swizzles: bijective, consistent write/read, flip only bits >= access size
__device__ __forceinline__ int swz32(int row, int col)  { return row * 32  + (col ^ ((row & 3) << 3)); }
__device__ __forceinline__ int swz64(int row, int col)  { return row * 64  + (col ^ ((row & 7) << 3)); }
__device__ __forceinline__ int swz128(int row, int col) { return row * 128 + (col ^ ((row & 7) << 3)); }

__device__ __forceinline__ bf16x8 cvt8p(f32x4 a, f32x4 c) {
  bf16x8 r;
#pragma unroll
  for (int j = 0; j < 4; ++j) { r[j] = (bf16)a[j]; r[4 + j] = (bf16)c[j]; }
  return r;
}

// ---------------- prologue: pack mask, bias, weights into d_ws --------------
// pw_b is stored in MFMA-A-fragment order: within each 32-wide k-block,
// element k = t*16+q*4+r lands at position q*8+t*4+r, so a b128 read at
// col kd*32+quad*8 IS the K32 A-frag. O is written with the same k-slot
// order, so the contraction is permutation-consistent.
__global__ __launch_bounds__(256)
void prep(const float* __restrict__ maskg, const float* __restrict__ rpb,
          const int* __restrict__ rel, const float* __restrict__ qkvw,
          const float* __restrict__ projw, bf16* __restrict__ mask_b,
          bf16* __restrict__ bias_b, bf16* __restrict__ qkvw_b,
          bf16* __restrict__ pw_b) {
  int id = blockIdx.x * 256 + threadIdx.x;
  if (id < 262144) {
    int c = id & 63, n = (id >> 6) & 63, win = id >> 12;
    int qd = c >> 4, mt = (c >> 2) & 3, r = c & 3;
    int m = mt * 16 + qd * 4 + r;
    float v = -30000.0f;
    if (n < NTOK && m < NTOK) v = maskg[((size_t)win * NTOK + n) * NTOK + m];
    mask_b[id] = (bf16)v;
  } else if (id < 262144 + 16384) {
    int t = id - 262144;
    int c = t & 63, h = (t >> 6) & 3, n = t >> 8;
    int qd = c >> 4, mt = (c >> 2) & 3, r = c & 3;
    int m = mt * 16 + qd * 4 + r;
    float v = 0.0f;
    if (n < NTOK && m < NTOK) v = rpb[rel[n * NTOK + m] * 4 + h];
    bias_b[t] = (bf16)v;
  } else if (id < 262144 + 16384 + 49152) {
    int t = id - (262144 + 16384);
    qkvw_b[t] = (bf16)qkvw[t];
  } else {
    int t = id - (262144 + 16384 + 49152);   // 0..16383
    int j = t >> 7, k = t & 127;
    int kb = k >> 5, u = k & 31;
    int tt = u >> 4, q = (u >> 2) & 3, r = u & 3;
    pw_b[j * 128 + kb * 32 + q * 8 + tt * 4 + r] = (bf16)projw[t];
  }
}

// ---------------- main kernel: 8 windows/block, 8 waves, 2 blocks/CU --------
// Phase A: wave w8 owns j-tile w8 of Q,K,V (weights in VGPRs, x from LDS).
// Phase B: wave (g2=w8&3, hp=w8>>2) does 2 heads for token group g2;
//   O (permuted) overlays Q rows (only the producing wave touches its rows);
//   next-window x (issued at iter top, nontemporal) is committed to X early.
// Phase C: proj via K32 with pre-permuted pw from global (L1-resident: all
//   streaming traffic is nontemporal). 3 barriers/window, hidden by 2 blocks.
__global__ __launch_bounds__(512, 4)
void winattn(const float* __restrict__ xg, const float* __restrict__ qkvb,
             const float* __restrict__ projb, const bf16* __restrict__ mask_b,
             const bf16* __restrict__ bias_b, const bf16* __restrict__ qkvw_b,
             const bf16* __restrict__ pw_b, float* __restrict__ out) {
  extern __shared__ bf16 smd[];
  const int tid  = threadIdx.x;
  const int w8   = tid >> 6;
  const int lane = tid & 63;
  const int ln15 = lane & 15;
  const int quad = lane >> 4;
  const int h_kv = w8 >> 1, t_kv = w8 & 1;   // phase A j-tile split
  const int g2   = w8 & 3,  hp   = w8 >> 2;  // phase B/C roles
  const int nq   = g2 * 16 + ln15;

  // ---- one-time: q/k/v weight fragments + biases into registers ----
  bf16x8 wqf[4], wkf[4], wvf[4];
#pragma unroll
  for (int ks = 0; ks < 4; ++ks) {
    wqf[ks] = *(const bf16x8*)&qkvw_b[(size_t)(           w8 * 16 + ln15) * DIMC + ks * 32 + quad * 8];
    wkf[ks] = *(const bf16x8*)&qkvw_b[(size_t)(DIMC     + w8 * 16 + ln15) * DIMC + ks * 32 + quad * 8];
    wvf[ks] = *(const bf16x8*)&qkvw_b[(size_t)(2 * DIMC + w8 * 16 + ln15) * DIMC + ks * 32 + quad * 8];
  }
  f32x4 qb = *(const f32x4*)&qkvb[w8 * 16 + quad * 4];
  f32x4 kb = *(const f32x4*)&qkvb[DIMC + w8 * 16 + quad * 4];
  float vb = qkvb[2 * DIMC + w8 * 16 + ln15];
  bf16x4 bias4[2][4];
#pragma unroll
  for (int hh = 0; hh < 2; ++hh)
#pragma unroll
    for (int mt = 0; mt < 4; ++mt)
      bias4[hh][mt] = *(const bf16x4*)&bias_b[((nq * 4 + hp * 2 + hh) << 6) + quad * 16 + mt * 4];

  const int r0 = w8 * 8 + quad, r1 = r0 + 4;

  // ---- prologue: stage x(window 0) into X ----
  {
    const float* x0 = xg + (size_t)(blockIdx.x << 3) * (NTOK * DIMC);
    const float* p0 = x0 + (r0 < NTOK ? r0 : NTOK - 1) * DIMC + ln15 * 8;
    const float* p1 = x0 + (r1 < NTOK ? r1 : NTOK - 1) * DIMC + ln15 * 8;
    f32x4 a0 = __builtin_nontemporal_load((const f32x4*)p0);
    f32x4 a1 = __builtin_nontemporal_load((const f32x4*)(p0 + 4));
    f32x4 a2 = __builtin_nontemporal_load((const f32x4*)p1);
    f32x4 a3 = __builtin_nontemporal_load((const f32x4*)(p1 + 4));
    *(bf16x8*)&smd[X_OFF + swz128(r0, ln15 * 8)] = cvt8p(a0, a1);
    *(bf16x8*)&smd[X_OFF + swz128(r1, ln15 * 8)] = cvt8p(a2, a3);
  }
  __syncthreads();

#pragma unroll 1
  for (int it = 0; it < 8; ++it) {
    const int b = (blockIdx.x << 3) + it;

    // ---- issue next-window x loads (nontemporal; land late phase B) ----
    const int nit = it < 7 ? it + 1 : 7;
    const float* xnb = xg + (size_t)((blockIdx.x << 3) + nit) * (NTOK * DIMC);
    const float* np0 = xnb + (r0 < NTOK ? r0 : NTOK - 1) * DIMC + ln15 * 8;
    const float* np1 = xnb + (r1 < NTOK ? r1 : NTOK - 1) * DIMC + ln15 * 8;
    f32x4 nx0 = __builtin_nontemporal_load((const f32x4*)np0);
    f32x4 nx1 = __builtin_nontemporal_load((const f32x4*)(np0 + 4));
    f32x4 nx2 = __builtin_nontemporal_load((const f32x4*)np1);
    f32x4 nx3 = __builtin_nontemporal_load((const f32x4*)(np1 + 4));

    // ---- mask prefetch (nontemporal, used in phase B) ----
    const bf16* mb = mask_b + (((size_t)(b & 63) * 64 + nq) << 6) + quad * 16;
    bf16x8 mk0 = __builtin_nontemporal_load((const bf16x8*)mb);
    bf16x8 mk1 = __builtin_nontemporal_load((const bf16x8*)(mb + 8));

    // ---- phase A: Q/K/V j-tile w8 for all 4 token groups (x from LDS) ----
#pragma unroll
    for (int g = 0; g < 4; ++g) {
      bf16x8 xf[4];
#pragma unroll
      for (int ks = 0; ks < 4; ++ks)
        xf[ks] = *(const bf16x8*)&smd[X_OFF + swz128(g * 16 + ln15, ks * 32 + quad * 8)];
      f32x4 aq = (f32x4)(0.0f), ak = (f32x4)(0.0f), av = (f32x4)(0.0f);
#pragma unroll
      for (int ks = 0; ks < 4; ++ks) {
        aq = mfmaK32(wqf[ks], xf[ks], aq);   // C[j][tok]
        ak = mfmaK32(wkf[ks], xf[ks], ak);   // C[j][tok]
        av = mfmaK32(xf[ks], wvf[ks], av);   // C[tok][j]
      }
      bf16x4 pq, pk, pv;
#pragma unroll
      for (int r = 0; r < 4; ++r) {
        pq[r] = (bf16)((aq[r] + qb[r]) * SCALE);
        pk[r] = (bf16)(ak[r] + kb[r]);
        pv[r] = (bf16)(av[r] + vb);
      }
      *(bf16x4*)&smd[QO_OFF + swz32(h_kv * 64 + g * 16 + ln15, t_kv * 16 + quad * 4)] = pq;
      *(bf16x4*)&smd[K_OFF  + swz32(h_kv * 64 + g * 16 + ln15, t_kv * 16 + quad * 4)] = pk;
      *(bf16x4*)&smd[VT_OFF + swz64(h_kv * 32 + t_kv * 16 + ln15, g * 16 + quad * 4)] = pv;
    }
    __syncthreads();   // Q,K,VT ready; all x reads done

    // ---- early B: commit prefetched next-x into X (x dead after A) ----
    *(bf16x8*)&smd[X_OFF + swz128(r0, ln15 * 8)] = cvt8p(nx0, nx1);
    *(bf16x8*)&smd[X_OFF + swz128(r1, ln15 * 8)] = cvt8p(nx2, nx3);

    // ---- phase B: 2 heads of attention for token group g2 ----
#pragma unroll
    for (int hh = 0; hh < 2; ++hh) {
      const int h = hp * 2 + hh;
      bf16x8 qB = *(const bf16x8*)&smd[QO_OFF + swz32(h * 64 + nq, quad * 8)];
      f32x4 st[4];
#pragma unroll
      for (int mt = 0; mt < 4; ++mt) {
        bf16x8 k8 = *(const bf16x8*)&smd[K_OFF + swz32(h * 64 + mt * 16 + ln15, quad * 8)];
        st[mt] = mfmaK32(k8, qB, (f32x4)(0.0f));
      }
      float ssum = 0.0f;
      bf16x4 pw[4];
#pragma unroll
      for (int mt = 0; mt < 4; ++mt)
#pragma unroll
        for (int r = 0; r < 4; ++r) {
          float mv = (mt < 2) ? (float)mk0[mt * 4 + r] : (float)mk1[(mt - 2) * 4 + r];
          float v = fminf(st[mt][r] + mv + (float)bias4[hh][mt][r], 60.0f);
          float p = __expf(v);
          pw[mt][r] = (bf16)p;
          ssum += p;
        }
      ssum += __shfl_xor(ssum, 16);
      ssum += __shfl_xor(ssum, 32);
      f32x4 oa0 = (f32x4)(0.0f), oa1 = (f32x4)(0.0f);
#pragma unroll
      for (int mt = 0; mt < 4; ++mt) {
        oa0 = mfmaK16(*(const bf16x4*)&smd[VT_OFF + swz64(h * 32 + ln15,      mt * 16 + quad * 4)], pw[mt], oa0);
        oa1 = mfmaK16(*(const bf16x4*)&smd[VT_OFF + swz64(h * 32 + 16 + ln15, mt * 16 + quad * 4)], pw[mt], oa1);
      }
      const float inv = 1.0f / ssum;
      bf16x8 o8;   // permuted k-slot order: [oa0 r0..3 | oa1 r0..3]
#pragma unroll
      for (int r = 0; r < 4; ++r) {
        o8[r]     = (bf16)(oa0[r] * inv);
        o8[4 + r] = (bf16)(oa1[r] * inv);
      }
      *(bf16x8*)&smd[QO_OFF + swz32(h * 64 + nq, quad * 8)] = o8;  // O overlays Q
    }
    __syncthreads();   // O ready + next-x staged

    // ---- phase C: proj (K32, pw pre-permuted, global/L1), jt-half hp ----
    bf16x8 o8r[4];
#pragma unroll
    for (int kd = 0; kd < 4; ++kd)
      o8r[kd] = *(const bf16x8*)&smd[QO_OFF + swz32(kd * 64 + nq, quad * 8)];
    float* og = out + (size_t)b * (NTOK * DIMC) + nq * DIMC;
#pragma unroll
    for (int j = 0; j < 4; ++j) {
      const int jt = hp * 4 + j;
      f32x4 acc = (f32x4)(0.0f);
#pragma unroll
      for (int kd = 0; kd < 4; ++kd) {
        bf16x8 a8 = *(const bf16x8*)&pw_b[(size_t)(jt * 16 + ln15) * 128 + kd * 32 + quad * 8];
        acc = mfmaK32(a8, o8r[kd], acc);
      }
      if (nq < NTOK) {
        f32x4 pbv = *(const f32x4*)&projb[jt * 16 + quad * 4];
        f32x4 y;
#pragma unroll
        for (int r = 0; r < 4; ++r) y[r] = acc[r] + pbv[r];
        __builtin_nontemporal_store(y, (f32x4*)&og[jt * 16 + quad * 4]);
      }
    }
    __syncthreads();   // C reads done before next A overwrites Q/K/VT
  }
}

extern "C" void kernel_launch(void* const* d_in, const int* in_sizes, int n_in,
                              void* d_out, int out_size, void* d_ws, size_t ws_size,
                              hipStream_t stream) {
  const float* x     = (const float*)d_in[0];
  const float* mask  = (const float*)d_in[1];
  const float* qkv_w = (const float*)d_in[2];
  const float* qkv_b = (const float*)d_in[3];
  const float* rpb   = (const float*)d_in[4];
  const float* prj_w = (const float*)d_in[5];
  const float* prj_b = (const float*)d_in[6];
  const int*   rel   = (const int*)d_in[7];
  float* out = (float*)d_out;

  bf16* ws_mask = (bf16*)d_ws;
  bf16* ws_bias = (bf16*)((char*)d_ws + WS_BIAS_OFF);
  bf16* ws_qkvw = (bf16*)((char*)d_ws + WS_QKVW_OFF);
  bf16* ws_pw   = (bf16*)((char*)d_ws + WS_PW_OFF);

  static int once = []() {
    hipFuncSetAttribute(reinterpret_cast<const void*>(winattn),
                        hipFuncAttributeMaxDynamicSharedMemorySize, SM_BYTES);
    return 0;
  }();
  (void)once;

  prep<<<1344, 256, 0, stream>>>(mask, rpb, rel, qkv_w, prj_w,
                                 ws_mask, ws_bias, ws_qkvw, ws_pw);
  winattn<<<512, 512, SM_BYTES, stream>>>(x, qkv_b, prj_b, ws_mask, ws_bias,
                                          ws_qkvw, ws_pw, out);
}

// Round 7
// 259.150 us; speedup vs baseline: 1.6552x; 1.6552x over previous
//
#include <hip/hip_runtime.h>
#include <hip/hip_bf16.h>
#include <stdint.h>

#define NTOK 49
#define DIMC 128
#define NHEAD 4
#define SCALE 0.17677669529663687f

typedef __bf16 bf16;
typedef __bf16 bf16x8 __attribute__((ext_vector_type(8)));
typedef __bf16 bf16x4 __attribute__((ext_vector_type(4)));
typedef float  f32x4  __attribute__((ext_vector_type(4)));
typedef short  s16x4  __attribute__((ext_vector_type(4)));

// ---- LDS (bf16 elems), padded strides, total 37888 elems = 75776 B ----
// -> 2 blocks/CU (160 KB / 75.8 KB). 16B-aligned rows where b128 is used.
// K  @0     rows [h*64+tok] stride 40 (K[tok][d]); b128 @ col quad*8 aligned
// QO @10240 rows [h*64+tok] stride 40: Q (A->B), then O permuted (B->C)
// VT @20480 rows [h*32+d ] stride 68 (V^T[d][tok]); b64 accesses
// X  @29184 rows [tok]     stride 136; b128 accesses 16B-aligned
// Word-stride 20 (K/QO): 16 consecutive rows -> 8 distinct 4-bank groups, 2-way.
#define K_OFF  0
#define QO_OFF 10240
#define VT_OFF 20480
#define X_OFF  29184
#define QK_S 40
#define VT_S 68
#define X_S  136
#define SM_BYTES (37888 * 2)

// d_ws layout (bytes): mask_b bf16 [64][64][64] @0 (524288);
// bias_b bf16 [64][4][64] @524288 (32768); qkvw_b @557056 (98304);
// pw_b (A-frag permuted) @655360 (32768)
#define WS_BIAS_OFF  524288
#define WS_QKVW_OFF  557056
#define WS_PW_OFF    655360

__device__ __forceinline__ f32x4 mfmaK32(bf16x8 a, bf16x8 b, f32x4 c) {
  return __builtin_amdgcn_mfma_f32_16x16x32_bf16(a, b, c, 0, 0, 0);
}
__device__ __forceinline__ f32x4 mfmaK16(bf16x4 a, bf16x4 b, f32x4 c) {
#if __has_builtin(__builtin_amdgcn_mfma_f32_16x16x16bf16_1k)
  return __builtin_amdgcn_mfma_f32_16x16x16bf16_1k(*(s16x4*)&a, *(s16x4*)&b, c,
                                                   0, 0, 0);
#else
  f32x4 d;
  asm("v_mfma_f32_16x16x16_bf16 %0, %1, %2, %3"
      : "=v"(d) : "v"(a), "v"(b), "v"(c));
  return d;
#endif
}
__device__ __forceinline__ bf16x8 cvt8p(f32x4 a, f32x4 c) {
  bf16x8 r;
#pragma unroll
  for (int j = 0; j < 4; ++j) { r[j] = (bf16)a[j]; r[4 + j] = (bf16)c[j]; }
  return r;
}

// ---------------- prologue: pack mask, bias, weights into d_ws --------------
// pw_b is stored in MFMA-A-fragment order: within each 32-wide k-block,
// element k = t*16+q*4+r lands at position q*8+t*4+r, so a b128 read at
// col kd*32+quad*8 IS the K32 A-frag. O is written with the same k-slot
// order, so the contraction is permutation-consistent.
__global__ __launch_bounds__(256)
void prep(const float* __restrict__ maskg, const float* __restrict__ rpb,
          const int* __restrict__ rel, const float* __restrict__ qkvw,
          const float* __restrict__ projw, bf16* __restrict__ mask_b,
          bf16* __restrict__ bias_b, bf16* __restrict__ qkvw_b,
          bf16* __restrict__ pw_b) {
  int id = blockIdx.x * 256 + threadIdx.x;
  if (id < 262144) {
    int c = id & 63, n = (id >> 6) & 63, win = id >> 12;
    int qd = c >> 4, mt = (c >> 2) & 3, r = c & 3;
    int m = mt * 16 + qd * 4 + r;
    float v = -30000.0f;
    if (n < NTOK && m < NTOK) v = maskg[((size_t)win * NTOK + n) * NTOK + m];
    mask_b[id] = (bf16)v;
  } else if (id < 262144 + 16384) {
    int t = id - 262144;
    int c = t & 63, h = (t >> 6) & 3, n = t >> 8;
    int qd = c >> 4, mt = (c >> 2) & 3, r = c & 3;
    int m = mt * 16 + qd * 4 + r;
    float v = 0.0f;
    if (n < NTOK && m < NTOK) v = rpb[rel[n * NTOK + m] * 4 + h];
    bias_b[t] = (bf16)v;
  } else if (id < 262144 + 16384 + 49152) {
    int t = id - (262144 + 16384);
    qkvw_b[t] = (bf16)qkvw[t];
  } else {
    int t = id - (262144 + 16384 + 49152);   // 0..16383
    int j = t >> 7, k = t & 127;
    int kb = k >> 5, u = k & 31;
    int tt = u >> 4, q = (u >> 2) & 3, r = u & 3;
    pw_b[j * 128 + kb * 32 + q * 8 + tt * 4 + r] = (bf16)projw[t];
  }
}

// ---------------- main kernel: 8 windows/block, 8 waves, 2 blocks/CU --------
// Phase A: wave w8 owns j-tile w8 of Q,K,V (weights in VGPRs, x from LDS).
// Phase B: wave (g2=w8&3, hp=w8>>2) does 2 heads for token group g2;
//   O (permuted) overlays Q rows (only the producing wave touches its rows);
//   next-window x (issued at iter top, nontemporal) committed to X early-B.
// Phase C: proj via K32 with pre-permuted pw from global (L1/L2-cached).
// NT hints ONLY on streaming x loads + out stores; mask/pw stay cacheable.
// launch_bounds(512,2): 128-VGPR budget -- kernel needs ~110, must NOT spill.
__global__ __launch_bounds__(512, 2)
void winattn(const float* __restrict__ xg, const float* __restrict__ qkvb,
             const float* __restrict__ projb, const bf16* __restrict__ mask_b,
             const bf16* __restrict__ bias_b, const bf16* __restrict__ qkvw_b,
             const bf16* __restrict__ pw_b, float* __restrict__ out) {
  extern __shared__ bf16 smd[];
  const int tid  = threadIdx.x;
  const int w8   = tid >> 6;
  const int lane = tid & 63;
  const int ln15 = lane & 15;
  const int quad = lane >> 4;
  const int h_kv = w8 >> 1, t_kv = w8 & 1;   // phase A j-tile split
  const int g2   = w8 & 3,  hp   = w8 >> 2;  // phase B/C roles
  const int nq   = g2 * 16 + ln15;

  // ---- one-time: q/k/v weight fragments + biases into registers ----
  bf16x8 wqf[4], wkf[4], wvf[4];
#pragma unroll
  for (int ks = 0; ks < 4; ++ks) {
    wqf[ks] = *(const bf16x8*)&qkvw_b[(size_t)(           w8 * 16 + ln15) * DIMC + ks * 32 + quad * 8];
    wkf[ks] = *(const bf16x8*)&qkvw_b[(size_t)(DIMC     + w8 * 16 + ln15) * DIMC + ks * 32 + quad * 8];
    wvf[ks] = *(const bf16x8*)&qkvw_b[(size_t)(2 * DIMC + w8 * 16 + ln15) * DIMC + ks * 32 + quad * 8];
  }
  f32x4 qb = *(const f32x4*)&qkvb[w8 * 16 + quad * 4];
  f32x4 kb = *(const f32x4*)&qkvb[DIMC + w8 * 16 + quad * 4];
  float vb = qkvb[2 * DIMC + w8 * 16 + ln15];
  bf16x4 bias4[2][4];
#pragma unroll
  for (int hh = 0; hh < 2; ++hh)
#pragma unroll
    for (int mt = 0; mt < 4; ++mt)
      bias4[hh][mt] = *(const bf16x4*)&bias_b[((nq * 4 + hp * 2 + hh) << 6) + quad * 16 + mt * 4];

  const int r0 = w8 * 8 + quad, r1 = r0 + 4;

  // ---- prologue: stage x(window 0) into X ----
  {
    const float* x0 = xg + (size_t)(blockIdx.x << 3) * (NTOK * DIMC);
    const float* p0 = x0 + (r0 < NTOK ? r0 : NTOK - 1) * DIMC + ln15 * 8;
    const float* p1 = x0 + (r1 < NTOK ? r1 : NTOK - 1) * DIMC + ln15 * 8;
    f32x4 a0 = __builtin_nontemporal_load((const f32x4*)p0);
    f32x4 a1 = __builtin_nontemporal_load((const f32x4*)(p0 + 4));
    f32x4 a2 = __builtin_nontemporal_load((const f32x4*)p1);
    f32x4 a3 = __builtin_nontemporal_load((const f32x4*)(p1 + 4));
    *(bf16x8*)&smd[X_OFF + r0 * X_S + ln15 * 8] = cvt8p(a0, a1);
    *(bf16x8*)&smd[X_OFF + r1 * X_S + ln15 * 8] = cvt8p(a2, a3);
  }
  __syncthreads();

#pragma unroll 1
  for (int it = 0; it < 8; ++it) {
    const int b = (blockIdx.x << 3) + it;

    // ---- issue next-window x loads (nontemporal; committed early-B) ----
    const int nit = it < 7 ? it + 1 : 7;
    const float* xnb = xg + (size_t)((blockIdx.x << 3) + nit) * (NTOK * DIMC);
    const float* np0 = xnb + (r0 < NTOK ? r0 : NTOK - 1) * DIMC + ln15 * 8;
    const float* np1 = xnb + (r1 < NTOK ? r1 : NTOK - 1) * DIMC + ln15 * 8;
    f32x4 nx0 = __builtin_nontemporal_load((const f32x4*)np0);
    f32x4 nx1 = __builtin_nontemporal_load((const f32x4*)(np0 + 4));
    f32x4 nx2 = __builtin_nontemporal_load((const f32x4*)np1);
    f32x4 nx3 = __builtin_nontemporal_load((const f32x4*)(np1 + 4));

    // ---- mask prefetch (cached: reused by 64 blocks per mask row) ----
    const bf16* mb = mask_b + (((size_t)(b & 63) * 64 + nq) << 6) + quad * 16;
    bf16x8 mk0 = *(const bf16x8*)mb;
    bf16x8 mk1 = *(const bf16x8*)(mb + 8);

    // ---- phase A: Q/K/V j-tile w8 for all 4 token groups (x from LDS) ----
#pragma unroll
    for (int g = 0; g < 4; ++g) {
      bf16x8 xf[4];
#pragma unroll
      for (int ks = 0; ks < 4; ++ks)
        xf[ks] = *(const bf16x8*)&smd[X_OFF + (g * 16 + ln15) * X_S + ks * 32 + quad * 8];
      f32x4 aq = (f32x4)(0.0f), ak = (f32x4)(0.0f), av = (f32x4)(0.0f);
#pragma unroll
      for (int ks = 0; ks < 4; ++ks) {
        aq = mfmaK32(wqf[ks], xf[ks], aq);   // C[j][tok]
        ak = mfmaK32(wkf[ks], xf[ks], ak);   // C[j][tok]
        av = mfmaK32(xf[ks], wvf[ks], av);   // C[tok][j]
      }
      bf16x4 pq, pk, pv;
#pragma unroll
      for (int r = 0; r < 4; ++r) {
        pq[r] = (bf16)((aq[r] + qb[r]) * SCALE);
        pk[r] = (bf16)(ak[r] + kb[r]);
        pv[r] = (bf16)(av[r] + vb);
      }
      const int rowqk = (h_kv * 64 + g * 16 + ln15) * QK_S + t_kv * 16 + quad * 4;
      *(bf16x4*)&smd[QO_OFF + rowqk] = pq;
      *(bf16x4*)&smd[K_OFF  + rowqk] = pk;
      *(bf16x4*)&smd[VT_OFF + (h_kv * 32 + t_kv * 16 + ln15) * VT_S + g * 16 + quad * 4] = pv;
    }
    __syncthreads();   // Q,K,VT ready; all x reads done

    // ---- early B: commit prefetched next-x into X (x dead after A) ----
    *(bf16x8*)&smd[X_OFF + r0 * X_S + ln15 * 8] = cvt8p(nx0, nx1);
    *(bf16x8*)&smd[X_OFF + r1 * X_S + ln15 * 8] = cvt8p(nx2, nx3);

    // ---- phase B: 2 heads of attention for token group g2 ----
#pragma unroll
    for (int hh = 0; hh < 2; ++hh) {
      const int h = hp * 2 + hh;
      bf16x8 qB = *(const bf16x8*)&smd[QO_OFF + (h * 64 + nq) * QK_S + quad * 8];
      f32x4 st[4];
#pragma unroll
      for (int mt = 0; mt < 4; ++mt) {
        bf16x8 k8 = *(const bf16x8*)&smd[K_OFF + (h * 64 + mt * 16 + ln15) * QK_S + quad * 8];
        st[mt] = mfmaK32(k8, qB, (f32x4)(0.0f));
      }
      float ssum = 0.0f;
      bf16x4 pw[4];
#pragma unroll
      for (int mt = 0; mt < 4; ++mt)
#pragma unroll
        for (int r = 0; r < 4; ++r) {
          float mv = (mt < 2) ? (float)mk0[mt * 4 + r] : (float)mk1[(mt - 2) * 4 + r];
          float v = fminf(st[mt][r] + mv + (float)bias4[hh][mt][r], 60.0f);
          float p = __expf(v);
          pw[mt][r] = (bf16)p;
          ssum += p;
        }
      ssum += __shfl_xor(ssum, 16);
      ssum += __shfl_xor(ssum, 32);
      f32x4 oa0 = (f32x4)(0.0f), oa1 = (f32x4)(0.0f);
#pragma unroll
      for (int mt = 0; mt < 4; ++mt) {
        oa0 = mfmaK16(*(const bf16x4*)&smd[VT_OFF + (h * 32 + ln15) * VT_S + mt * 16 + quad * 4], pw[mt], oa0);
        oa1 = mfmaK16(*(const bf16x4*)&smd[VT_OFF + (h * 32 + 16 + ln15) * VT_S + mt * 16 + quad * 4], pw[mt], oa1);
      }
      const float inv = 1.0f / ssum;
      bf16x8 o8;   // permuted k-slot order: [oa0 r0..3 | oa1 r0..3]
#pragma unroll
      for (int r = 0; r < 4; ++r) {
        o8[r]     = (bf16)(oa0[r] * inv);
        o8[4 + r] = (bf16)(oa1[r] * inv);
      }
      *(bf16x8*)&smd[QO_OFF + (h * 64 + nq) * QK_S + quad * 8] = o8;  // O overlays Q
    }
    __syncthreads();   // O ready + next-x staged

    // ---- phase C: proj (K32, pw pre-permuted, global/L1), jt-half hp ----
    bf16x8 o8r[4];
#pragma unroll
    for (int kd = 0; kd < 4; ++kd)
      o8r[kd] = *(const bf16x8*)&smd[QO_OFF + (kd * 64 + nq) * QK_S + quad * 8];
    float* og = out + (size_t)b * (NTOK * DIMC) + nq * DIMC;
#pragma unroll
    for (int j = 0; j < 4; ++j) {
      const int jt = hp * 4 + j;
      f32x4 acc = (f32x4)(0.0f);
#pragma unroll
      for (int kd = 0; kd < 4; ++kd) {
        bf16x8 a8 = *(const bf16x8*)&pw_b[(size_t)(jt * 16 + ln15) * 128 + kd * 32 + quad * 8];
        acc = mfmaK32(a8, o8r[kd], acc);
      }
      if (nq < NTOK) {
        f32x4 pbv = *(const f32x4*)&projb[jt * 16 + quad * 4];
        f32x4 y;
#pragma unroll
        for (int r = 0; r < 4; ++r) y[r] = acc[r] + pbv[r];
        __builtin_nontemporal_store(y, (f32x4*)&og[jt * 16 + quad * 4]);
      }
    }
    __syncthreads();   // C reads done before next A overwrites Q/K/VT
  }
}

extern "C" void kernel_launch(void* const* d_in, const int* in_sizes, int n_in,
                              void* d_out, int out_size, void* d_ws, size_t ws_size,
                              hipStream_t stream) {
  const float* x     = (const float*)d_in[0];
  const float* mask  = (const float*)d_in[1];
  const float* qkv_w = (const float*)d_in[2];
  const float* qkv_b = (const float*)d_in[3];
  const float* rpb   = (const float*)d_in[4];
  const float* prj_w = (const float*)d_in[5];
  const float* prj_b = (const float*)d_in[6];
  const int*   rel   = (const int*)d_in[7];
  float* out = (float*)d_out;

  bf16* ws_mask = (bf16*)d_ws;
  bf16* ws_bias = (bf16*)((char*)d_ws + WS_BIAS_OFF);
  bf16* ws_qkvw = (bf16*)((char*)d_ws + WS_QKVW_OFF);
  bf16* ws_pw   = (bf16*)((char*)d_ws + WS_PW_OFF);

  static int once = []() {
    hipFuncSetAttribute(reinterpret_cast<const void*>(winattn),
                        hipFuncAttributeMaxDynamicSharedMemorySize, SM_BYTES);
    return 0;
  }();
  (void)once;

  prep<<<1344, 256, 0, stream>>>(mask, rpb, rel, qkv_w, prj_w,
                                 ws_mask, ws_bias, ws_qkvw, ws_pw);
  winattn<<<512, 512, SM_BYTES, stream>>>(x, qkv_b, prj_b, ws_mask, ws_bias,
                                          ws_qkvw, ws_pw, out);
}